// Round 9
// baseline (402.135 us; speedup 1.0000x reference)
//
#include <hip/hip_runtime.h>
#include <hip/hip_fp16.h>

#define TPB 256
#define CHUNK 1024   // elements per scan block (256 threads x 4)
#define AGG_BLOCKS 2048   // persistent-wave grid for the pull kernels

typedef _Float16 half8 __attribute__((ext_vector_type(8)));
typedef float    f32x4 __attribute__((ext_vector_type(4)));

// ---------------- K1: per-node in-degree count (global atomics) + W fragment prep ----------------
// Edge order in the final CSR is atomic-scheduling dependent — same as the previous
// partition/finalize chain (both used atomicAdd fill counters), so no determinism lost.

__global__ __launch_bounds__(256) void deg_wprep_kernel(const int* __restrict__ dst,
                                                        int* __restrict__ deg,
                                                        const float* __restrict__ W1,
                                                        const float* __restrict__ W2,
                                                        _Float16* __restrict__ wf1g,
                                                        _Float16* __restrict__ wf2g,
                                                        int e) {
    const int t = threadIdx.x;
    if (blockIdx.x == 0) {            // W1 -> MFMA fragment blob (extra duty)
        for (int f = t; f < 8 * 4 * 64; f += 256) {
            int c = f >> 8, i = (f >> 6) & 3, lane = f & 63;
            int quad = lane >> 4, nn = lane & 15;
            const float* wp = W1 + (size_t)(i * 32 + quad * 8) * 128 + c * 16 + nn;
            half8 hv;
#pragma unroll
            for (int j = 0; j < 8; ++j) hv[j] = (_Float16)wp[(size_t)j * 128];
            ((half8*)wf1g)[f] = hv;
        }
    } else if (blockIdx.x == 1) {     // W2 -> MFMA fragment blob
        for (int f = t; f < 4 * 4 * 64; f += 256) {
            int c = f >> 8, i = (f >> 6) & 3, lane = f & 63;
            int quad = lane >> 4, nn = lane & 15;
            const float* wp = W2 + (size_t)(i * 32 + quad * 8) * 64 + c * 16 + nn;
            half8 hv;
#pragma unroll
            for (int j = 0; j < 8; ++j) hv[j] = (_Float16)wp[(size_t)j * 64];
            ((half8*)wf2g)[f] = hv;
        }
    }
    const int idx = (blockIdx.x * 256 + t) * 4;
    if (idx + 3 < e) {
        int4 d = *(const int4*)(dst + idx);
        atomicAdd(&deg[d.x], 1);
        atomicAdd(&deg[d.y], 1);
        atomicAdd(&deg[d.z], 1);
        atomicAdd(&deg[d.w], 1);
    } else {
        for (int i = idx; i < e; ++i) atomicAdd(&deg[dst[i]], 1);
    }
}

// ---------------- two-level exclusive scan over deg -> row_ptr ----------------

__global__ __launch_bounds__(256) void scanA_kernel(const int* __restrict__ cnt,
                                                    int* __restrict__ row_ptr,
                                                    int* __restrict__ chunk_sums, int n) {
    __shared__ int ls[256];
    const int t    = threadIdx.x;
    const int base = blockIdx.x * CHUNK;
    const int idx  = base + t * 4;
    int4 v = make_int4(0, 0, 0, 0);
    if (idx + 3 < n) v = *(const int4*)(cnt + idx);
    else {
        if (idx + 0 < n) v.x = cnt[idx + 0];
        if (idx + 1 < n) v.y = cnt[idx + 1];
        if (idx + 2 < n) v.z = cnt[idx + 2];
        if (idx + 3 < n) v.w = cnt[idx + 3];
    }
    int s0 = v.x, s1 = s0 + v.y, s2 = s1 + v.z, s3 = s2 + v.w;
    ls[t] = s3;
    __syncthreads();
    for (int off = 1; off < 256; off <<= 1) {
        int xv = (t >= off) ? ls[t - off] : 0;
        __syncthreads();
        ls[t] += xv;
        __syncthreads();
    }
    int excl = (t == 0) ? 0 : ls[t - 1];
    if (idx + 0 < n) row_ptr[idx + 0] = excl;
    if (idx + 1 < n) row_ptr[idx + 1] = excl + s0;
    if (idx + 2 < n) row_ptr[idx + 2] = excl + s1;
    if (idx + 3 < n) row_ptr[idx + 3] = excl + s2;
    if (t == 255) chunk_sums[blockIdx.x] = ls[255];
}

__global__ __launch_bounds__(256) void scanB_kernel(int* __restrict__ chunk_sums, int nch) {
    __shared__ int ls[256];
    const int t = threadIdx.x;
    ls[t] = (t < nch) ? chunk_sums[t] : 0;
    __syncthreads();
    for (int off = 1; off < 256; off <<= 1) {
        int xv = (t >= off) ? ls[t - off] : 0;
        __syncthreads();
        ls[t] += xv;
        __syncthreads();
    }
    if (t < nch) chunk_sums[t] = (t == 0) ? 0 : ls[t - 1];  // exclusive
}

// ---------------- K4: apply chunk offsets; write fill copy; dinv from deg ----------------

__global__ __launch_bounds__(256) void fixup_kernel(int* __restrict__ row_ptr,
                                                    int* __restrict__ fill,
                                                    const int* __restrict__ deg,
                                                    float* __restrict__ dinv,
                                                    const int* __restrict__ chunk_sums,
                                                    int n, int e) {
    const int t    = threadIdx.x;
    const int base = blockIdx.x * CHUNK;
    const int off  = chunk_sums[blockIdx.x];
    const int idx  = base + t * 4;
    if (idx + 3 < n) {
        int4 rp = *(const int4*)(row_ptr + idx);
        int4 dg = *(const int4*)(deg + idx);
        rp.x += off; rp.y += off; rp.z += off; rp.w += off;
        *(int4*)(row_ptr + idx) = rp;
        *(int4*)(fill + idx)    = rp;
        float4 dv;
        dv.x = rsqrtf((float)(dg.x + 1));
        dv.y = rsqrtf((float)(dg.y + 1));
        dv.z = rsqrtf((float)(dg.z + 1));
        dv.w = rsqrtf((float)(dg.w + 1));
        *(float4*)(dinv + idx) = dv;
    } else {
        for (int i = idx; i < n; ++i) {
            int rp = row_ptr[i] + off;
            row_ptr[i] = rp;
            fill[i]    = rp;
            dinv[i]    = rsqrtf((float)(deg[i] + 1));
        }
    }
    if (blockIdx.x == 0 && t == 0) row_ptr[n] = e;
}

// ---------------- K5: edge placement via atomic fill counters ----------------

__global__ __launch_bounds__(256) void place_kernel(const int* __restrict__ src,
                                                    const int* __restrict__ dst,
                                                    int* __restrict__ fill,
                                                    int* __restrict__ csr_src, int e) {
    const int idx = (blockIdx.x * 256 + threadIdx.x) * 4;
    if (idx + 3 < e) {
        int4 d = *(const int4*)(dst + idx);
        int4 s = *(const int4*)(src + idx);
        int p0 = atomicAdd(&fill[d.x], 1); csr_src[p0] = s.x;
        int p1 = atomicAdd(&fill[d.y], 1); csr_src[p1] = s.y;
        int p2 = atomicAdd(&fill[d.z], 1); csr_src[p2] = s.z;
        int p3 = atomicAdd(&fill[d.w], 1); csr_src[p3] = s.w;
    } else {
        for (int i = idx; i < e; ++i) {
            int p = atomicAdd(&fill[dst[i]], 1);
            csr_src[p] = src[i];
        }
    }
}

// ---------------- dense transform via MFMA: HS(fp16) = dinv[row] * (relu?)(X) @ W ----------------
// A[m=lane&15][k=quad*8+j]; C/D: col=lane&15, row=quad*4+reg.
// W arrives as a pre-converted fragment blob -> staging is a pure uint4 copy.

template <int M, bool RELU, typename XT>
__global__ __launch_bounds__(256) void gemm_mfma_kernel(const XT* __restrict__ X,
                                                        const _Float16* __restrict__ Wfg,
                                                        const float* __restrict__ dinv,
                                                        __half* __restrict__ H, int nrows) {
    constexpr int NC = M / 16;                 // col-tiles: 8 (M=128) / 4 (M=64)
    __shared__ __align__(16) _Float16 Wf[NC * 4 * 64 * 8];   // 32 KB / 16 KB

    const int tid = threadIdx.x;
    const uint4* wb = (const uint4*)Wfg;
    for (int f = tid; f < NC * 4 * 64; f += 256)
        ((uint4*)Wf)[f] = wb[f];
    __syncthreads();

    const int  wave = tid >> 6, lane = tid & 63;
    const int  quad = lane >> 4, n16 = lane & 15;
    const long rowbase = (long)blockIdx.x * 64 + wave * 16;

    long arow = rowbase + n16;
    const XT* xrow = X + (size_t)(arow < nrows ? arow : 0) * 128;
    half8 a[4];
    if constexpr (sizeof(XT) == 4) {   // fp32 input
        const float4* xr = (const float4*)xrow;
#pragma unroll
        for (int i = 0; i < 4; ++i) {
            float4 x0 = xr[i * 8 + quad * 2];
            float4 x1 = xr[i * 8 + quad * 2 + 1];
            if (RELU) {
                x0.x = fmaxf(x0.x, 0.f); x0.y = fmaxf(x0.y, 0.f);
                x0.z = fmaxf(x0.z, 0.f); x0.w = fmaxf(x0.w, 0.f);
                x1.x = fmaxf(x1.x, 0.f); x1.y = fmaxf(x1.y, 0.f);
                x1.z = fmaxf(x1.z, 0.f); x1.w = fmaxf(x1.w, 0.f);
            }
            half8 hv;
            hv[0] = (_Float16)x0.x; hv[1] = (_Float16)x0.y;
            hv[2] = (_Float16)x0.z; hv[3] = (_Float16)x0.w;
            hv[4] = (_Float16)x1.x; hv[5] = (_Float16)x1.y;
            hv[6] = (_Float16)x1.z; hv[7] = (_Float16)x1.w;
            a[i] = hv;
        }
    } else {                           // fp16 input (out1)
        const half8* xr = (const half8*)xrow;
#pragma unroll
        for (int i = 0; i < 4; ++i) {
            half8 hv = xr[i * 4 + quad];
            if (RELU) {
#pragma unroll
                for (int j = 0; j < 8; ++j)
                    hv[j] = (hv[j] > (_Float16)0) ? hv[j] : (_Float16)0;
            }
            a[i] = hv;
        }
    }

    float dv[4];
#pragma unroll
    for (int r = 0; r < 4; ++r) {
        long orow = rowbase + quad * 4 + r;
        dv[r] = (orow < nrows) ? dinv[orow] : 0.f;
    }

    for (int c = 0; c < NC; ++c) {
        f32x4 acc = {0.f, 0.f, 0.f, 0.f};
#pragma unroll
        for (int i = 0; i < 4; ++i) {
            half8 b = ((const half8*)Wf)[(c * 4 + i) * 64 + lane];
            acc = __builtin_amdgcn_mfma_f32_16x16x32_f16(a[i], b, acc, 0, 0, 0);
        }
#pragma unroll
        for (int r = 0; r < 4; ++r) {
            long orow = rowbase + quad * 4 + r;
            if (orow < nrows)
                H[orow * M + c * 16 + n16] = __float2half(acc[r] * dv[r]);
        }
    }
}

// ---------------- vectorized gather helper: add 4 half2 (one uint4) into 4 float2 ----------------

__device__ __forceinline__ void add_u4(float2* a, const uint4& u) {
    float2 v0 = __half22float2(*(const __half2*)&u.x);
    float2 v1 = __half22float2(*(const __half2*)&u.y);
    float2 v2 = __half22float2(*(const __half2*)&u.z);
    float2 v3 = __half22float2(*(const __half2*)&u.w);
    a[0].x += v0.x; a[0].y += v0.y;
    a[1].x += v1.x; a[1].y += v1.y;
    a[2].x += v2.x; a[2].y += v2.y;
    a[3].x += v3.x; a[3].y += v3.y;
}

// ---------------- pull aggregation layer 1 (R5-proven, unchanged) ----------------

__global__ __launch_bounds__(TPB) void agg_pull128_kernel(const __half* __restrict__ hs,
                                                          const int* __restrict__ csr_src,
                                                          const int* __restrict__ row_ptr,
                                                          const float* __restrict__ dinv,
                                                          const float* __restrict__ bias,
                                                          __half* __restrict__ out, int n) {
    const int wid  = blockIdx.x * (TPB / 64) + (threadIdx.x >> 6);
    const int NW   = gridDim.x * (TPB / 64);
    const int lane = threadIdx.x & 63;
    const int q    = lane >> 4;    // edge slot 0..3
    const int sl   = lane & 15;    // 16-B chunk within the 256-B row
    if (wid >= n) return;
    const uint4* up   = (const uint4*)hs;    // row = 16 uint4
    const uint4* upsl = up + sl;

    const float4* bp = (const float4*)bias;  // loop-invariant bias
    const float4 bb0 = bp[2 * sl], bb1 = bp[2 * sl + 1];

    int b0 = row_ptr[wid], e0 = row_ptr[wid + 1];
    int nA = wid + NW;
    int b1 = 0, e1 = 0;
    if (nA < n) { b1 = row_ptr[nA]; e1 = row_ptr[nA + 1]; }
    int m0 = e0 - b0; if (m0 > 64) m0 = 64;
    int idx0 = (lane < m0) ? csr_src[b0 + lane] : 0;
    uint4 self0 = make_uint4(0, 0, 0, 0);
    if (q == 0) self0 = up[(size_t)wid * 16 + sl];
    float dv0 = dinv[wid];

    for (int ni = wid; ni < n; ni += NW) {
        const int n1 = ni + NW, n2 = ni + 2 * NW;
        int b2 = 0, e2 = 0;
        if (n2 < n) { b2 = row_ptr[n2]; e2 = row_ptr[n2 + 1]; }
        int idx1 = 0; uint4 self1 = make_uint4(0, 0, 0, 0); float dv1 = 0.f;
        if (n1 < n) {
            int m1 = e1 - b1; if (m1 > 64) m1 = 64;
            idx1 = (lane < m1) ? csr_src[b1 + lane] : 0;
            if (q == 0) self1 = up[(size_t)n1 * 16 + sl];
            dv1 = dinv[n1];
        }
        int m = e0 - b0; if (m > 64) m = 64;
        int sA0 = __shfl(idx0, q);
        int sA1 = __shfl(idx0, 4 + q);
        int sA2 = __shfl(idx0, 8 + q);
        int sA3 = __shfl(idx0, 12 + q);
        int sB0 = __shfl(idx0, 16 + q);
        int sB1 = __shfl(idx0, 20 + q);
        int sB2 = __shfl(idx0, 24 + q);
        int sB3 = __shfl(idx0, 28 + q);
        uint4 uA0 = upsl[(size_t)(unsigned)sA0 * 16];
        uint4 uA1 = upsl[(size_t)(unsigned)sA1 * 16];
        uint4 uA2 = upsl[(size_t)(unsigned)sA2 * 16];
        uint4 uA3 = upsl[(size_t)(unsigned)sA3 * 16];
        uint4 uB0 = upsl[(size_t)(unsigned)sB0 * 16];
        uint4 uB1 = upsl[(size_t)(unsigned)sB1 * 16];
        uint4 uB2 = upsl[(size_t)(unsigned)sB2 * 16];
        uint4 uB3 = upsl[(size_t)(unsigned)sB3 * 16];
        float2 a0[4], a1[4];
#pragma unroll
        for (int k = 0; k < 4; ++k) { a0[k] = make_float2(0.f, 0.f); a1[k] = make_float2(0.f, 0.f); }
        if (m >= 32) {
            add_u4(a0, uA0); add_u4(a1, uA1); add_u4(a0, uA2); add_u4(a1, uA3);
            add_u4(a0, uB0); add_u4(a1, uB1); add_u4(a0, uB2); add_u4(a1, uB3);
        } else {
            if (q < m)      add_u4(a0, uA0);
            if (4 + q < m)  add_u4(a1, uA1);
            if (8 + q < m)  add_u4(a0, uA2);
            if (12 + q < m) add_u4(a1, uA3);
            if (16 + q < m) add_u4(a0, uB0);
            if (20 + q < m) add_u4(a1, uB1);
            if (24 + q < m) add_u4(a0, uB2);
            if (28 + q < m) add_u4(a1, uB3);
        }
        for (int j = 32; j < m; j += 16) {
            int s0 = __shfl(idx0, j + q);
            int s1 = __shfl(idx0, j + 4 + q);
            int s2 = __shfl(idx0, j + 8 + q);
            int s3 = __shfl(idx0, j + 12 + q);
            uint4 u0 = upsl[(size_t)(unsigned)s0 * 16];
            uint4 u1 = upsl[(size_t)(unsigned)s1 * 16];
            uint4 u2 = upsl[(size_t)(unsigned)s2 * 16];
            uint4 u3 = upsl[(size_t)(unsigned)s3 * 16];
            if (j + q < m)      add_u4(a0, u0);
            if (j + 4 + q < m)  add_u4(a1, u1);
            if (j + 8 + q < m)  add_u4(a0, u2);
            if (j + 12 + q < m) add_u4(a1, u3);
        }
        for (int base = b0 + 64; base < e0; base += 64) {
            int mm = e0 - base; if (mm > 64) mm = 64;
            int idxv = (lane < mm) ? csr_src[base + lane] : 0;
            for (int j = 0; j < mm; j += 16) {
                int s0 = __shfl(idxv, j + q);
                int s1 = __shfl(idxv, j + 4 + q);
                int s2 = __shfl(idxv, j + 8 + q);
                int s3 = __shfl(idxv, j + 12 + q);
                uint4 u0 = upsl[(size_t)(unsigned)s0 * 16];
                uint4 u1 = upsl[(size_t)(unsigned)s1 * 16];
                uint4 u2 = upsl[(size_t)(unsigned)s2 * 16];
                uint4 u3 = upsl[(size_t)(unsigned)s3 * 16];
                if (j + q < mm)      add_u4(a0, u0);
                if (j + 4 + q < mm)  add_u4(a1, u1);
                if (j + 8 + q < mm)  add_u4(a0, u2);
                if (j + 12 + q < mm) add_u4(a1, u3);
            }
        }
#pragma unroll
        for (int k = 0; k < 4; ++k) { a0[k].x += a1[k].x; a0[k].y += a1[k].y; }
#pragma unroll
        for (int k = 0; k < 4; ++k) {
            a0[k].x += __shfl(a0[k].x, lane ^ 16);
            a0[k].y += __shfl(a0[k].y, lane ^ 16);
            a0[k].x += __shfl(a0[k].x, lane ^ 32);
            a0[k].y += __shfl(a0[k].y, lane ^ 32);
        }
        if (q == 0) {
            float2 v0 = __half22float2(*(const __half2*)&self0.x);
            float2 v1 = __half22float2(*(const __half2*)&self0.y);
            float2 v2 = __half22float2(*(const __half2*)&self0.z);
            float2 v3 = __half22float2(*(const __half2*)&self0.w);
            __half2 h0 = __floats2half2_rn(bb0.x + dv0 * (a0[0].x + v0.x),
                                           bb0.y + dv0 * (a0[0].y + v0.y));
            __half2 h1 = __floats2half2_rn(bb0.z + dv0 * (a0[1].x + v1.x),
                                           bb0.w + dv0 * (a0[1].y + v1.y));
            __half2 h2 = __floats2half2_rn(bb1.x + dv0 * (a0[2].x + v2.x),
                                           bb1.y + dv0 * (a0[2].y + v2.y));
            __half2 h3 = __floats2half2_rn(bb1.z + dv0 * (a0[3].x + v3.x),
                                           bb1.w + dv0 * (a0[3].y + v3.y));
            uint4 ov;
            ov.x = *(const unsigned*)&h0; ov.y = *(const unsigned*)&h1;
            ov.z = *(const unsigned*)&h2; ov.w = *(const unsigned*)&h3;
            ((uint4*)out)[(size_t)ni * 16 + sl] = ov;
        }
        b0 = b1; e0 = e1; idx0 = idx1; self0 = self1; dv0 = dv1;
        b1 = b2; e1 = e2;
    }
}

// ---------------- pull aggregation layer 2: TWO NODES PER WAVE (R8-proven, unchanged) ----------------

__global__ __launch_bounds__(TPB) void agg_pull64_kernel(const __half* __restrict__ hs,
                                                         const int* __restrict__ csr_src,
                                                         const int* __restrict__ row_ptr,
                                                         const float* __restrict__ dinv,
                                                         const float* __restrict__ bias,
                                                         float* __restrict__ out, int n) {
    const int wid  = blockIdx.x * (TPB / 64) + (threadIdx.x >> 6);   // pair index base
    const int NW   = gridDim.x * (TPB / 64);
    const int lane = threadIdx.x & 63;
    const int h    = lane >> 5;          // which node of the pair
    const int lh   = lane & 31;          // lane within half
    const int qh   = lh >> 3;            // edge slot 0..3 within half
    const int sl   = lane & 7;           // 16-B chunk within the 128-B row
    const int hb   = h << 5;             // half base lane for shfl
    const int npairs = (n + 1) >> 1;
    if (wid >= npairs) return;
    const uint4* up   = (const uint4*)hs;    // row = 8 uint4
    const uint4* upsl = up + sl;

    const float4* bp = (const float4*)bias;
    const float4 bb0 = bp[2 * sl], bb1 = bp[2 * sl + 1];

    int np0 = 2 * wid + h;
    int b0 = 0, e0 = 0;
    if (np0 < n) { b0 = row_ptr[np0]; e0 = row_ptr[np0 + 1]; }
    int pA = wid + NW;
    int b1 = 0, e1 = 0;
    {
        int npA = 2 * pA + h;
        if (pA < npairs && npA < n) { b1 = row_ptr[npA]; e1 = row_ptr[npA + 1]; }
    }
    int m0 = e0 - b0; if (m0 > 32) m0 = 32;
    int idx0 = (lh < m0) ? csr_src[b0 + lh] : 0;
    uint4 self0 = make_uint4(0, 0, 0, 0);
    if (qh == 0 && np0 < n) self0 = up[(size_t)np0 * 8 + sl];
    float dv0 = (np0 < n) ? dinv[np0] : 0.f;

    for (int pp = wid; pp < npairs; pp += NW) {
        const int p1 = pp + NW, p2 = pp + 2 * NW;
        const int np = 2 * pp + h;           // this half's node
        int b2 = 0, e2 = 0;
        if (p2 < npairs) {
            int np2 = 2 * p2 + h;
            if (np2 < n) { b2 = row_ptr[np2]; e2 = row_ptr[np2 + 1]; }
        }
        int idx1 = 0; uint4 self1 = make_uint4(0, 0, 0, 0); float dv1 = 0.f;
        if (p1 < npairs) {
            int np1 = 2 * p1 + h;
            if (np1 < n) {
                int m1 = e1 - b1; if (m1 > 32) m1 = 32;
                idx1 = (lh < m1) ? csr_src[b1 + lh] : 0;
                if (qh == 0) self1 = up[(size_t)np1 * 8 + sl];
                dv1 = dinv[np1];
            }
        }
        int m = e0 - b0; if (m > 32) m = 32;
        int s0 = __shfl(idx0, hb + qh);
        int s1 = __shfl(idx0, hb + 4 + qh);
        int s2 = __shfl(idx0, hb + 8 + qh);
        int s3 = __shfl(idx0, hb + 12 + qh);
        int s4 = __shfl(idx0, hb + 16 + qh);
        int s5 = __shfl(idx0, hb + 20 + qh);
        int s6 = __shfl(idx0, hb + 24 + qh);
        int s7 = __shfl(idx0, hb + 28 + qh);
        uint4 u0 = upsl[(size_t)(unsigned)s0 * 8];
        uint4 u1 = upsl[(size_t)(unsigned)s1 * 8];
        uint4 u2 = upsl[(size_t)(unsigned)s2 * 8];
        uint4 u3 = upsl[(size_t)(unsigned)s3 * 8];
        uint4 u4 = upsl[(size_t)(unsigned)s4 * 8];
        uint4 u5 = upsl[(size_t)(unsigned)s5 * 8];
        uint4 u6 = upsl[(size_t)(unsigned)s6 * 8];
        uint4 u7 = upsl[(size_t)(unsigned)s7 * 8];
        float2 a0[4], a1[4];
#pragma unroll
        for (int k = 0; k < 4; ++k) { a0[k] = make_float2(0.f, 0.f); a1[k] = make_float2(0.f, 0.f); }
        if (m >= 32) {
            add_u4(a0, u0); add_u4(a1, u1); add_u4(a0, u2); add_u4(a1, u3);
            add_u4(a0, u4); add_u4(a1, u5); add_u4(a0, u6); add_u4(a1, u7);
        } else {
            if (qh < m)      add_u4(a0, u0);
            if (4 + qh < m)  add_u4(a1, u1);
            if (8 + qh < m)  add_u4(a0, u2);
            if (12 + qh < m) add_u4(a1, u3);
            if (16 + qh < m) add_u4(a0, u4);
            if (20 + qh < m) add_u4(a1, u5);
            if (24 + qh < m) add_u4(a0, u6);
            if (28 + qh < m) add_u4(a1, u7);
        }
        for (int base = b0 + 32; base < e0; base += 32) {
            int mm = e0 - base; if (mm > 32) mm = 32;
            int idxv = (lh < mm) ? csr_src[base + lh] : 0;
            for (int j = 0; j < mm; j += 8) {
                int t0 = __shfl(idxv, hb + j + qh);
                int t1 = __shfl(idxv, hb + j + 4 + qh);
                uint4 v0 = upsl[(size_t)(unsigned)t0 * 8];
                uint4 v1 = upsl[(size_t)(unsigned)t1 * 8];
                if (j + qh < mm)     add_u4(a0, v0);
                if (j + 4 + qh < mm) add_u4(a1, v1);
            }
        }
#pragma unroll
        for (int k = 0; k < 4; ++k) { a0[k].x += a1[k].x; a0[k].y += a1[k].y; }
#pragma unroll
        for (int k = 0; k < 4; ++k) {
            a0[k].x += __shfl(a0[k].x, lane ^ 8);
            a0[k].y += __shfl(a0[k].y, lane ^ 8);
            a0[k].x += __shfl(a0[k].x, lane ^ 16);
            a0[k].y += __shfl(a0[k].y, lane ^ 16);
        }
        if (qh == 0 && np < n) {
            float2 v0 = __half22float2(*(const __half2*)&self0.x);
            float2 v1 = __half22float2(*(const __half2*)&self0.y);
            float2 v2 = __half22float2(*(const __half2*)&self0.z);
            float2 v3 = __half22float2(*(const __half2*)&self0.w);
            float4 o0, o1;
            o0.x = bb0.x + dv0 * (a0[0].x + v0.x);
            o0.y = bb0.y + dv0 * (a0[0].y + v0.y);
            o0.z = bb0.z + dv0 * (a0[1].x + v1.x);
            o0.w = bb0.w + dv0 * (a0[1].y + v1.y);
            o1.x = bb1.x + dv0 * (a0[2].x + v2.x);
            o1.y = bb1.y + dv0 * (a0[2].y + v2.y);
            o1.z = bb1.z + dv0 * (a0[3].x + v3.x);
            o1.w = bb1.w + dv0 * (a0[3].y + v3.y);
            ((float4*)out)[(size_t)np * 16 + 2 * sl]     = o0;
            ((float4*)out)[(size_t)np * 16 + 2 * sl + 1] = o1;
        }
        b0 = b1; e0 = e1; idx0 = idx1; self0 = self1; dv0 = dv1;
        b1 = b2; e1 = e2;
    }
}

// ---------------- launcher ----------------

extern "C" void kernel_launch(void* const* d_in, const int* in_sizes, int n_in,
                              void* d_out, int out_size, void* d_ws, size_t ws_size,
                              hipStream_t stream) {
    const float* x  = (const float*)d_in[0];
    const int*   ei = (const int*)d_in[1];   // int32 on the wire
    const float* W1 = (const float*)d_in[2];
    const float* b1 = (const float*)d_in[3];
    const float* W2 = (const float*)d_in[4];
    const float* b2 = (const float*)d_in[5];
    float* out = (float*)d_out;

    const int N = in_sizes[0] / 128;   // 100000
    const int E = in_sizes[1] / 2;     // 1600000
    const int* srcv = ei;
    const int* dstv = ei + E;

    const int NCH_N  = (N + CHUNK - 1) / CHUNK;       // 98 scan chunks over nodes
    const int EBLK   = (E + 1023) / 1024;             // 1563 edge blocks (4 edges/thread)

    // workspace layout (segments padded to 64 B; hs1/out1 16-B aligned for dwordx4)
    char* p = (char*)d_ws;
    int*      row_ptr    = (int*)p;      p += (((size_t)N + 64) * 4 + 63) & ~(size_t)63;
    int*      deg        = (int*)p;      p += (((size_t)N + 64) * 4 + 63) & ~(size_t)63;
    int*      fill       = (int*)p;      p += (((size_t)N + 64) * 4 + 63) & ~(size_t)63;
    int*      chunk_sums = (int*)p;      p += 1024;
    int*      csr_src    = (int*)p;      p += ((size_t)E * 4 + 63) & ~(size_t)63;
    float*    dinv       = (float*)p;    p += (((size_t)N + 64) * 4 + 63) & ~(size_t)63;
    _Float16* wf1g       = (_Float16*)p; p += 8 * 4 * 64 * 16;   // 32 KB blob
    _Float16* wf2g       = (_Float16*)p; p += 4 * 4 * 64 * 16;   // 16 KB blob
    __half*   hs1        = (__half*)p;   p += (size_t)N * 128 * 2;
    __half*   out1       = (__half*)p;   p += (size_t)N * 128 * 2;
    __half*   hs2        = hs1;             // hs1 dead once out1 complete

    // zero the degree counters
    hipMemsetAsync(deg, 0, (size_t)N * 4, stream);

    // ---- CSR build: deg (atomic) -> scan -> fixup -> place ----
    deg_wprep_kernel<<<EBLK, 256, 0, stream>>>(dstv, deg, W1, W2, wf1g, wf2g, E);
    scanA_kernel<<<NCH_N, 256, 0, stream>>>(deg, row_ptr, chunk_sums, N);
    scanB_kernel<<<1, 256, 0, stream>>>(chunk_sums, NCH_N);
    fixup_kernel<<<NCH_N, 256, 0, stream>>>(row_ptr, fill, deg, dinv, chunk_sums, N, E);
    place_kernel<<<EBLK, 256, 0, stream>>>(srcv, dstv, fill, csr_src, E);

    // ---- layer 1: MFMA GEMM (fp32 in, fp16 out), agg -> fp16 out1 ----
    gemm_mfma_kernel<128, false, float><<<(N + 63) / 64, 256, 0, stream>>>(x, wf1g, dinv, hs1, N);
    agg_pull128_kernel<<<AGG_BLOCKS, TPB, 0, stream>>>(hs1, csr_src, row_ptr, dinv, b1, out1, N);

    // ---- layer 2: MFMA GEMM (fp16 in w/ fused ReLU), agg -> fp32 d_out ----
    gemm_mfma_kernel<64, true, _Float16><<<(N + 63) / 64, 256, 0, stream>>>(
        (const _Float16*)out1, wf2g, dinv, hs2, N);
    agg_pull64_kernel<<<AGG_BLOCKS, TPB, 0, stream>>>(hs2, csr_src, row_ptr, dinv, b2, out, N);
}

// Round 10
// 259.046 us; speedup vs baseline: 1.5524x; 1.5524x over previous
//
#include <hip/hip_runtime.h>
#include <hip/hip_fp16.h>

#define TPB 256
#define CHUNK 1024   // elements per scan block (256 threads x 4)
#define EPB 4096     // edges per partition block
#define CSHIFT 8     // coarse bucket = 256 nodes
#define AGG_BLOCKS 2048   // persistent-wave grid for the pull kernels

typedef _Float16 half8 __attribute__((ext_vector_type(8)));
typedef float    f32x4 __attribute__((ext_vector_type(4)));

// ---------------- two-level exclusive scan (in-place safe; chunk offsets applied by consumers) ----

__global__ __launch_bounds__(256) void scanA_kernel(const int* __restrict__ cnt,
                                                    int* __restrict__ row_ptr,
                                                    int* __restrict__ chunk_sums, int n) {
    __shared__ int ls[256];
    const int t    = threadIdx.x;
    const int base = blockIdx.x * CHUNK;
    const int idx  = base + t * 4;
    int4 v = make_int4(0, 0, 0, 0);
    if (idx + 3 < n) v = *(const int4*)(cnt + idx);
    else {
        if (idx + 0 < n) v.x = cnt[idx + 0];
        if (idx + 1 < n) v.y = cnt[idx + 1];
        if (idx + 2 < n) v.z = cnt[idx + 2];
        if (idx + 3 < n) v.w = cnt[idx + 3];
    }
    int s0 = v.x, s1 = s0 + v.y, s2 = s1 + v.z, s3 = s2 + v.w;
    ls[t] = s3;
    __syncthreads();
    for (int off = 1; off < 256; off <<= 1) {
        int xv = (t >= off) ? ls[t - off] : 0;
        __syncthreads();
        ls[t] += xv;
        __syncthreads();
    }
    int excl = (t == 0) ? 0 : ls[t - 1];
    if (idx + 0 < n) row_ptr[idx + 0] = excl;
    if (idx + 1 < n) row_ptr[idx + 1] = excl + s0;
    if (idx + 2 < n) row_ptr[idx + 2] = excl + s1;
    if (idx + 3 < n) row_ptr[idx + 3] = excl + s2;
    if (t == 255) chunk_sums[blockIdx.x] = ls[255];
}

__global__ __launch_bounds__(256) void scanB_kernel(int* __restrict__ chunk_sums, int nch) {
    __shared__ int ls[256];
    const int t = threadIdx.x;
    ls[t] = (t < nch) ? chunk_sums[t] : 0;
    __syncthreads();
    for (int off = 1; off < 256; off <<= 1) {
        int xv = (t >= off) ? ls[t - off] : 0;
        __syncthreads();
        ls[t] += xv;
        __syncthreads();
    }
    if (t < nch) chunk_sums[t] = (t == 0) ? 0 : ls[t - 1];  // exclusive
}

// ---------------- CSR build: deterministic counting partition ----------------
// hist blocks 0/1 additionally convert W1/W2 to MFMA fragment blobs (extra duty,
// saves one launch; mechanism validated in R9's deg_wprep).

__global__ __launch_bounds__(256) void hist_kernel(const int* __restrict__ dst,
                                                   int* __restrict__ hist_g,
                                                   const float* __restrict__ W1,
                                                   const float* __restrict__ W2,
                                                   _Float16* __restrict__ wf1g,
                                                   _Float16* __restrict__ wf2g,
                                                   int e, int nbc, int nblk) {
    __shared__ int hs[512];
    const int t = threadIdx.x;
    if (blockIdx.x == 0) {            // W1 -> MFMA fragment blob
        for (int f = t; f < 8 * 4 * 64; f += 256) {
            int c = f >> 8, i = (f >> 6) & 3, lane = f & 63;
            int quad = lane >> 4, nn = lane & 15;
            const float* wp = W1 + (size_t)(i * 32 + quad * 8) * 128 + c * 16 + nn;
            half8 hv;
#pragma unroll
            for (int j = 0; j < 8; ++j) hv[j] = (_Float16)wp[(size_t)j * 128];
            ((half8*)wf1g)[f] = hv;
        }
    } else if (blockIdx.x == 1) {     // W2 -> MFMA fragment blob
        for (int f = t; f < 4 * 4 * 64; f += 256) {
            int c = f >> 8, i = (f >> 6) & 3, lane = f & 63;
            int quad = lane >> 4, nn = lane & 15;
            const float* wp = W2 + (size_t)(i * 32 + quad * 8) * 64 + c * 16 + nn;
            half8 hv;
#pragma unroll
            for (int j = 0; j < 8; ++j) hv[j] = (_Float16)wp[(size_t)j * 64];
            ((half8*)wf2g)[f] = hv;
        }
    }
    for (int i = t; i < nbc; i += 256) hs[i] = 0;
    __syncthreads();
    const int e0  = blockIdx.x * EPB;
    const int lim = min(e0 + EPB, e);
    for (int i = e0 + t; i < lim; i += 256)
        atomicAdd(&hs[dst[i] >> CSHIFT], 1);
    __syncthreads();
    for (int b = t; b < nbc; b += 256)
        hist_g[b * nblk + blockIdx.x] = hs[b];
}

// pairs entries are PACKED 32-bit: (dst_local << 17) | src   (N=100000 < 2^17)
__global__ __launch_bounds__(256) void partition_kernel(const int* __restrict__ src,
                                                        const int* __restrict__ dst,
                                                        const int* __restrict__ hist_scan,
                                                        const int* __restrict__ chunk_sums,
                                                        int* __restrict__ pairs,
                                                        int e, int nbc, int nblk) {
    __shared__ int  hs[512];
    __shared__ int  lscan[512];
    __shared__ int  lfill[512];
    __shared__ int  base_s[512];
    __shared__ int  ls[256];
    __shared__ int2 sp[EPB];   // 32 KB staging
    const int t = threadIdx.x;
    for (int i = t; i < nbc; i += 256) { hs[i] = 0; lfill[i] = 0; }
    __syncthreads();
    const int e0  = blockIdx.x * EPB;
    const int lim = min(e0 + EPB, e);
    for (int i = e0 + t; i < lim; i += 256)
        atomicAdd(&hs[dst[i] >> CSHIFT], 1);
    __syncthreads();
    int v0 = (2 * t     < nbc) ? hs[2 * t]     : 0;
    int v1 = (2 * t + 1 < nbc) ? hs[2 * t + 1] : 0;
    ls[t] = v0 + v1;
    __syncthreads();
    for (int off = 1; off < 256; off <<= 1) {
        int xv = (t >= off) ? ls[t - off] : 0;
        __syncthreads();
        ls[t] += xv;
        __syncthreads();
    }
    int excl = (t == 0) ? 0 : ls[t - 1];
    if (2 * t     < nbc) lscan[2 * t]     = excl;
    if (2 * t + 1 < nbc) lscan[2 * t + 1] = excl + v0;
    for (int b = t; b < nbc; b += 256) {
        int hidx = b * nblk + blockIdx.x;
        base_s[b] = hist_scan[hidx] + chunk_sums[hidx >> 10];
    }
    __syncthreads();
    for (int i = e0 + t; i < lim; i += 256) {
        int d = dst[i];
        int b = d >> CSHIFT;
        int r = atomicAdd(&lfill[b], 1);
        sp[lscan[b] + r] = make_int2(src[i], d);
    }
    __syncthreads();
    const int cnt = lim - e0;
    for (int i = t; i < cnt; i += 256) {
        int2 pr = sp[i];
        int  b  = pr.y >> CSHIFT;
        pairs[base_s[b] + (i - lscan[b])] = pr.x | ((pr.y & 255) << 17);
    }
}

// One block per 256-node bucket: per-node count + scan in LDS, then write
// row_ptr, dinv, and place csr_src. No global atomics anywhere.
__global__ __launch_bounds__(256) void bucket_finalize_kernel(const int* __restrict__ pairs,
                                                              const int* __restrict__ hist_scan,
                                                              const int* __restrict__ chunk_sums,
                                                              int* __restrict__ row_ptr,
                                                              float* __restrict__ dinv,
                                                              int* __restrict__ csr_src,
                                                              int n, int e, int nbc, int nblk) {
    __shared__ int cnt_s[256];
    __shared__ int fill[256];
    __shared__ int ls[256];
    const int b   = blockIdx.x;
    const int nb0 = b << CSHIFT;
    const int t   = threadIdx.x;
    const int h0  = b * nblk;
    const int r0  = hist_scan[h0] + chunk_sums[h0 >> 10];      // bucket start
    int r1 = e;
    if (b + 1 < nbc) {
        const int h1 = (b + 1) * nblk;
        r1 = hist_scan[h1] + chunk_sums[h1 >> 10];
    }
    cnt_s[t] = 0;
    __syncthreads();
    for (int i = r0 + t; i < r1; i += 256)
        atomicAdd(&cnt_s[pairs[i] >> 17], 1);
    __syncthreads();
    int c = cnt_s[t];
    ls[t] = c;
    __syncthreads();
    for (int off = 1; off < 256; off <<= 1) {
        int xv = (t >= off) ? ls[t - off] : 0;
        __syncthreads();
        ls[t] += xv;
        __syncthreads();
    }
    int excl = (t == 0) ? 0 : ls[t - 1];
    int node = nb0 + t;
    if (node < n) {
        row_ptr[node] = r0 + excl;
        dinv[node]    = rsqrtf((float)(c + 1));   // +1 self-loop
    }
    fill[t] = r0 + excl;
    __syncthreads();
    for (int i = r0 + t; i < r1; i += 256) {
        int pr = pairs[i];
        int p  = atomicAdd(&fill[pr >> 17], 1);
        csr_src[p] = pr & 0x1FFFF;
    }
    if (b == 0 && t == 0) row_ptr[n] = e;
}

// ---------------- dense transform via MFMA: HS(fp16) = dinv[row] * (relu?)(X) @ W ----------------
// A[m=lane&15][k=quad*8+j]; C/D: col=lane&15, row=quad*4+reg.
// W arrives as a pre-converted fragment blob -> staging is a pure uint4 copy.

template <int M, bool RELU, typename XT>
__global__ __launch_bounds__(256) void gemm_mfma_kernel(const XT* __restrict__ X,
                                                        const _Float16* __restrict__ Wfg,
                                                        const float* __restrict__ dinv,
                                                        __half* __restrict__ H, int nrows) {
    constexpr int NC = M / 16;                 // col-tiles: 8 (M=128) / 4 (M=64)
    __shared__ __align__(16) _Float16 Wf[NC * 4 * 64 * 8];   // 32 KB / 16 KB

    const int tid = threadIdx.x;
    const uint4* wb = (const uint4*)Wfg;
    for (int f = tid; f < NC * 4 * 64; f += 256)
        ((uint4*)Wf)[f] = wb[f];
    __syncthreads();

    const int  wave = tid >> 6, lane = tid & 63;
    const int  quad = lane >> 4, n16 = lane & 15;
    const long rowbase = (long)blockIdx.x * 64 + wave * 16;

    long arow = rowbase + n16;
    const XT* xrow = X + (size_t)(arow < nrows ? arow : 0) * 128;
    half8 a[4];
    if constexpr (sizeof(XT) == 4) {   // fp32 input
        const float4* xr = (const float4*)xrow;
#pragma unroll
        for (int i = 0; i < 4; ++i) {
            float4 x0 = xr[i * 8 + quad * 2];
            float4 x1 = xr[i * 8 + quad * 2 + 1];
            if (RELU) {
                x0.x = fmaxf(x0.x, 0.f); x0.y = fmaxf(x0.y, 0.f);
                x0.z = fmaxf(x0.z, 0.f); x0.w = fmaxf(x0.w, 0.f);
                x1.x = fmaxf(x1.x, 0.f); x1.y = fmaxf(x1.y, 0.f);
                x1.z = fmaxf(x1.z, 0.f); x1.w = fmaxf(x1.w, 0.f);
            }
            half8 hv;
            hv[0] = (_Float16)x0.x; hv[1] = (_Float16)x0.y;
            hv[2] = (_Float16)x0.z; hv[3] = (_Float16)x0.w;
            hv[4] = (_Float16)x1.x; hv[5] = (_Float16)x1.y;
            hv[6] = (_Float16)x1.z; hv[7] = (_Float16)x1.w;
            a[i] = hv;
        }
    } else {                           // fp16 input (out1)
        const half8* xr = (const half8*)xrow;
#pragma unroll
        for (int i = 0; i < 4; ++i) {
            half8 hv = xr[i * 4 + quad];
            if (RELU) {
#pragma unroll
                for (int j = 0; j < 8; ++j)
                    hv[j] = (hv[j] > (_Float16)0) ? hv[j] : (_Float16)0;
            }
            a[i] = hv;
        }
    }

    float dv[4];
#pragma unroll
    for (int r = 0; r < 4; ++r) {
        long orow = rowbase + quad * 4 + r;
        dv[r] = (orow < nrows) ? dinv[orow] : 0.f;
    }

    for (int c = 0; c < NC; ++c) {
        f32x4 acc = {0.f, 0.f, 0.f, 0.f};
#pragma unroll
        for (int i = 0; i < 4; ++i) {
            half8 b = ((const half8*)Wf)[(c * 4 + i) * 64 + lane];
            acc = __builtin_amdgcn_mfma_f32_16x16x32_f16(a[i], b, acc, 0, 0, 0);
        }
#pragma unroll
        for (int r = 0; r < 4; ++r) {
            long orow = rowbase + quad * 4 + r;
            if (orow < nrows)
                H[orow * M + c * 16 + n16] = __float2half(acc[r] * dv[r]);
        }
    }
}

// ---------------- vectorized gather helper: add 4 half2 (one uint4) into 4 float2 ----------------

__device__ __forceinline__ void add_u4(float2* a, const uint4& u) {
    float2 v0 = __half22float2(*(const __half2*)&u.x);
    float2 v1 = __half22float2(*(const __half2*)&u.y);
    float2 v2 = __half22float2(*(const __half2*)&u.z);
    float2 v3 = __half22float2(*(const __half2*)&u.w);
    a[0].x += v0.x; a[0].y += v0.y;
    a[1].x += v1.x; a[1].y += v1.y;
    a[2].x += v2.x; a[2].y += v2.y;
    a[3].x += v3.x; a[3].y += v3.y;
}

// ---------------- pull aggregation layer 1 (R5-proven, unchanged) ----------------

__global__ __launch_bounds__(TPB) void agg_pull128_kernel(const __half* __restrict__ hs,
                                                          const int* __restrict__ csr_src,
                                                          const int* __restrict__ row_ptr,
                                                          const float* __restrict__ dinv,
                                                          const float* __restrict__ bias,
                                                          __half* __restrict__ out, int n) {
    const int wid  = blockIdx.x * (TPB / 64) + (threadIdx.x >> 6);
    const int NW   = gridDim.x * (TPB / 64);
    const int lane = threadIdx.x & 63;
    const int q    = lane >> 4;    // edge slot 0..3
    const int sl   = lane & 15;    // 16-B chunk within the 256-B row
    if (wid >= n) return;
    const uint4* up   = (const uint4*)hs;    // row = 16 uint4
    const uint4* upsl = up + sl;

    const float4* bp = (const float4*)bias;  // loop-invariant bias
    const float4 bb0 = bp[2 * sl], bb1 = bp[2 * sl + 1];

    int b0 = row_ptr[wid], e0 = row_ptr[wid + 1];
    int nA = wid + NW;
    int b1 = 0, e1 = 0;
    if (nA < n) { b1 = row_ptr[nA]; e1 = row_ptr[nA + 1]; }
    int m0 = e0 - b0; if (m0 > 64) m0 = 64;
    int idx0 = (lane < m0) ? csr_src[b0 + lane] : 0;
    uint4 self0 = make_uint4(0, 0, 0, 0);
    if (q == 0) self0 = up[(size_t)wid * 16 + sl];
    float dv0 = dinv[wid];

    for (int ni = wid; ni < n; ni += NW) {
        const int n1 = ni + NW, n2 = ni + 2 * NW;
        int b2 = 0, e2 = 0;
        if (n2 < n) { b2 = row_ptr[n2]; e2 = row_ptr[n2 + 1]; }
        int idx1 = 0; uint4 self1 = make_uint4(0, 0, 0, 0); float dv1 = 0.f;
        if (n1 < n) {
            int m1 = e1 - b1; if (m1 > 64) m1 = 64;
            idx1 = (lane < m1) ? csr_src[b1 + lane] : 0;
            if (q == 0) self1 = up[(size_t)n1 * 16 + sl];
            dv1 = dinv[n1];
        }
        int m = e0 - b0; if (m > 64) m = 64;
        int sA0 = __shfl(idx0, q);
        int sA1 = __shfl(idx0, 4 + q);
        int sA2 = __shfl(idx0, 8 + q);
        int sA3 = __shfl(idx0, 12 + q);
        int sB0 = __shfl(idx0, 16 + q);
        int sB1 = __shfl(idx0, 20 + q);
        int sB2 = __shfl(idx0, 24 + q);
        int sB3 = __shfl(idx0, 28 + q);
        uint4 uA0 = upsl[(size_t)(unsigned)sA0 * 16];
        uint4 uA1 = upsl[(size_t)(unsigned)sA1 * 16];
        uint4 uA2 = upsl[(size_t)(unsigned)sA2 * 16];
        uint4 uA3 = upsl[(size_t)(unsigned)sA3 * 16];
        uint4 uB0 = upsl[(size_t)(unsigned)sB0 * 16];
        uint4 uB1 = upsl[(size_t)(unsigned)sB1 * 16];
        uint4 uB2 = upsl[(size_t)(unsigned)sB2 * 16];
        uint4 uB3 = upsl[(size_t)(unsigned)sB3 * 16];
        float2 a0[4], a1[4];
#pragma unroll
        for (int k = 0; k < 4; ++k) { a0[k] = make_float2(0.f, 0.f); a1[k] = make_float2(0.f, 0.f); }
        if (m >= 32) {
            add_u4(a0, uA0); add_u4(a1, uA1); add_u4(a0, uA2); add_u4(a1, uA3);
            add_u4(a0, uB0); add_u4(a1, uB1); add_u4(a0, uB2); add_u4(a1, uB3);
        } else {
            if (q < m)      add_u4(a0, uA0);
            if (4 + q < m)  add_u4(a1, uA1);
            if (8 + q < m)  add_u4(a0, uA2);
            if (12 + q < m) add_u4(a1, uA3);
            if (16 + q < m) add_u4(a0, uB0);
            if (20 + q < m) add_u4(a1, uB1);
            if (24 + q < m) add_u4(a0, uB2);
            if (28 + q < m) add_u4(a1, uB3);
        }
        for (int j = 32; j < m; j += 16) {
            int s0 = __shfl(idx0, j + q);
            int s1 = __shfl(idx0, j + 4 + q);
            int s2 = __shfl(idx0, j + 8 + q);
            int s3 = __shfl(idx0, j + 12 + q);
            uint4 u0 = upsl[(size_t)(unsigned)s0 * 16];
            uint4 u1 = upsl[(size_t)(unsigned)s1 * 16];
            uint4 u2 = upsl[(size_t)(unsigned)s2 * 16];
            uint4 u3 = upsl[(size_t)(unsigned)s3 * 16];
            if (j + q < m)      add_u4(a0, u0);
            if (j + 4 + q < m)  add_u4(a1, u1);
            if (j + 8 + q < m)  add_u4(a0, u2);
            if (j + 12 + q < m) add_u4(a1, u3);
        }
        for (int base = b0 + 64; base < e0; base += 64) {
            int mm = e0 - base; if (mm > 64) mm = 64;
            int idxv = (lane < mm) ? csr_src[base + lane] : 0;
            for (int j = 0; j < mm; j += 16) {
                int s0 = __shfl(idxv, j + q);
                int s1 = __shfl(idxv, j + 4 + q);
                int s2 = __shfl(idxv, j + 8 + q);
                int s3 = __shfl(idxv, j + 12 + q);
                uint4 u0 = upsl[(size_t)(unsigned)s0 * 16];
                uint4 u1 = upsl[(size_t)(unsigned)s1 * 16];
                uint4 u2 = upsl[(size_t)(unsigned)s2 * 16];
                uint4 u3 = upsl[(size_t)(unsigned)s3 * 16];
                if (j + q < mm)      add_u4(a0, u0);
                if (j + 4 + q < mm)  add_u4(a1, u1);
                if (j + 8 + q < mm)  add_u4(a0, u2);
                if (j + 12 + q < mm) add_u4(a1, u3);
            }
        }
#pragma unroll
        for (int k = 0; k < 4; ++k) { a0[k].x += a1[k].x; a0[k].y += a1[k].y; }
#pragma unroll
        for (int k = 0; k < 4; ++k) {
            a0[k].x += __shfl(a0[k].x, lane ^ 16);
            a0[k].y += __shfl(a0[k].y, lane ^ 16);
            a0[k].x += __shfl(a0[k].x, lane ^ 32);
            a0[k].y += __shfl(a0[k].y, lane ^ 32);
        }
        if (q == 0) {
            float2 v0 = __half22float2(*(const __half2*)&self0.x);
            float2 v1 = __half22float2(*(const __half2*)&self0.y);
            float2 v2 = __half22float2(*(const __half2*)&self0.z);
            float2 v3 = __half22float2(*(const __half2*)&self0.w);
            __half2 h0 = __floats2half2_rn(bb0.x + dv0 * (a0[0].x + v0.x),
                                           bb0.y + dv0 * (a0[0].y + v0.y));
            __half2 h1 = __floats2half2_rn(bb0.z + dv0 * (a0[1].x + v1.x),
                                           bb0.w + dv0 * (a0[1].y + v1.y));
            __half2 h2 = __floats2half2_rn(bb1.x + dv0 * (a0[2].x + v2.x),
                                           bb1.y + dv0 * (a0[2].y + v2.y));
            __half2 h3 = __floats2half2_rn(bb1.z + dv0 * (a0[3].x + v3.x),
                                           bb1.w + dv0 * (a0[3].y + v3.y));
            uint4 ov;
            ov.x = *(const unsigned*)&h0; ov.y = *(const unsigned*)&h1;
            ov.z = *(const unsigned*)&h2; ov.w = *(const unsigned*)&h3;
            ((uint4*)out)[(size_t)ni * 16 + sl] = ov;
        }
        b0 = b1; e0 = e1; idx0 = idx1; self0 = self1; dv0 = dv1;
        b1 = b2; e1 = e2;
    }
}

// ---------------- pull aggregation layer 2: TWO NODES PER WAVE (R8-proven, unchanged) ----------------

__global__ __launch_bounds__(TPB) void agg_pull64_kernel(const __half* __restrict__ hs,
                                                         const int* __restrict__ csr_src,
                                                         const int* __restrict__ row_ptr,
                                                         const float* __restrict__ dinv,
                                                         const float* __restrict__ bias,
                                                         float* __restrict__ out, int n) {
    const int wid  = blockIdx.x * (TPB / 64) + (threadIdx.x >> 6);   // pair index base
    const int NW   = gridDim.x * (TPB / 64);
    const int lane = threadIdx.x & 63;
    const int h    = lane >> 5;          // which node of the pair
    const int lh   = lane & 31;          // lane within half
    const int qh   = lh >> 3;            // edge slot 0..3 within half
    const int sl   = lane & 7;           // 16-B chunk within the 128-B row
    const int hb   = h << 5;             // half base lane for shfl
    const int npairs = (n + 1) >> 1;
    if (wid >= npairs) return;
    const uint4* up   = (const uint4*)hs;    // row = 8 uint4
    const uint4* upsl = up + sl;

    const float4* bp = (const float4*)bias;
    const float4 bb0 = bp[2 * sl], bb1 = bp[2 * sl + 1];

    int np0 = 2 * wid + h;
    int b0 = 0, e0 = 0;
    if (np0 < n) { b0 = row_ptr[np0]; e0 = row_ptr[np0 + 1]; }
    int pA = wid + NW;
    int b1 = 0, e1 = 0;
    {
        int npA = 2 * pA + h;
        if (pA < npairs && npA < n) { b1 = row_ptr[npA]; e1 = row_ptr[npA + 1]; }
    }
    int m0 = e0 - b0; if (m0 > 32) m0 = 32;
    int idx0 = (lh < m0) ? csr_src[b0 + lh] : 0;
    uint4 self0 = make_uint4(0, 0, 0, 0);
    if (qh == 0 && np0 < n) self0 = up[(size_t)np0 * 8 + sl];
    float dv0 = (np0 < n) ? dinv[np0] : 0.f;

    for (int pp = wid; pp < npairs; pp += NW) {
        const int p1 = pp + NW, p2 = pp + 2 * NW;
        const int np = 2 * pp + h;           // this half's node
        int b2 = 0, e2 = 0;
        if (p2 < npairs) {
            int np2 = 2 * p2 + h;
            if (np2 < n) { b2 = row_ptr[np2]; e2 = row_ptr[np2 + 1]; }
        }
        int idx1 = 0; uint4 self1 = make_uint4(0, 0, 0, 0); float dv1 = 0.f;
        if (p1 < npairs) {
            int np1 = 2 * p1 + h;
            if (np1 < n) {
                int m1 = e1 - b1; if (m1 > 32) m1 = 32;
                idx1 = (lh < m1) ? csr_src[b1 + lh] : 0;
                if (qh == 0) self1 = up[(size_t)np1 * 8 + sl];
                dv1 = dinv[np1];
            }
        }
        int m = e0 - b0; if (m > 32) m = 32;
        int s0 = __shfl(idx0, hb + qh);
        int s1 = __shfl(idx0, hb + 4 + qh);
        int s2 = __shfl(idx0, hb + 8 + qh);
        int s3 = __shfl(idx0, hb + 12 + qh);
        int s4 = __shfl(idx0, hb + 16 + qh);
        int s5 = __shfl(idx0, hb + 20 + qh);
        int s6 = __shfl(idx0, hb + 24 + qh);
        int s7 = __shfl(idx0, hb + 28 + qh);
        uint4 u0 = upsl[(size_t)(unsigned)s0 * 8];
        uint4 u1 = upsl[(size_t)(unsigned)s1 * 8];
        uint4 u2 = upsl[(size_t)(unsigned)s2 * 8];
        uint4 u3 = upsl[(size_t)(unsigned)s3 * 8];
        uint4 u4 = upsl[(size_t)(unsigned)s4 * 8];
        uint4 u5 = upsl[(size_t)(unsigned)s5 * 8];
        uint4 u6 = upsl[(size_t)(unsigned)s6 * 8];
        uint4 u7 = upsl[(size_t)(unsigned)s7 * 8];
        float2 a0[4], a1[4];
#pragma unroll
        for (int k = 0; k < 4; ++k) { a0[k] = make_float2(0.f, 0.f); a1[k] = make_float2(0.f, 0.f); }
        if (m >= 32) {
            add_u4(a0, u0); add_u4(a1, u1); add_u4(a0, u2); add_u4(a1, u3);
            add_u4(a0, u4); add_u4(a1, u5); add_u4(a0, u6); add_u4(a1, u7);
        } else {
            if (qh < m)      add_u4(a0, u0);
            if (4 + qh < m)  add_u4(a1, u1);
            if (8 + qh < m)  add_u4(a0, u2);
            if (12 + qh < m) add_u4(a1, u3);
            if (16 + qh < m) add_u4(a0, u4);
            if (20 + qh < m) add_u4(a1, u5);
            if (24 + qh < m) add_u4(a0, u6);
            if (28 + qh < m) add_u4(a1, u7);
        }
        for (int base = b0 + 32; base < e0; base += 32) {
            int mm = e0 - base; if (mm > 32) mm = 32;
            int idxv = (lh < mm) ? csr_src[base + lh] : 0;
            for (int j = 0; j < mm; j += 8) {
                int t0 = __shfl(idxv, hb + j + qh);
                int t1 = __shfl(idxv, hb + j + 4 + qh);
                uint4 v0 = upsl[(size_t)(unsigned)t0 * 8];
                uint4 v1 = upsl[(size_t)(unsigned)t1 * 8];
                if (j + qh < mm)     add_u4(a0, v0);
                if (j + 4 + qh < mm) add_u4(a1, v1);
            }
        }
#pragma unroll
        for (int k = 0; k < 4; ++k) { a0[k].x += a1[k].x; a0[k].y += a1[k].y; }
#pragma unroll
        for (int k = 0; k < 4; ++k) {
            a0[k].x += __shfl(a0[k].x, lane ^ 8);
            a0[k].y += __shfl(a0[k].y, lane ^ 8);
            a0[k].x += __shfl(a0[k].x, lane ^ 16);
            a0[k].y += __shfl(a0[k].y, lane ^ 16);
        }
        if (qh == 0 && np < n) {
            float2 v0 = __half22float2(*(const __half2*)&self0.x);
            float2 v1 = __half22float2(*(const __half2*)&self0.y);
            float2 v2 = __half22float2(*(const __half2*)&self0.z);
            float2 v3 = __half22float2(*(const __half2*)&self0.w);
            float4 o0, o1;
            o0.x = bb0.x + dv0 * (a0[0].x + v0.x);
            o0.y = bb0.y + dv0 * (a0[0].y + v0.y);
            o0.z = bb0.z + dv0 * (a0[1].x + v1.x);
            o0.w = bb0.w + dv0 * (a0[1].y + v1.y);
            o1.x = bb1.x + dv0 * (a0[2].x + v2.x);
            o1.y = bb1.y + dv0 * (a0[2].y + v2.y);
            o1.z = bb1.z + dv0 * (a0[3].x + v3.x);
            o1.w = bb1.w + dv0 * (a0[3].y + v3.y);
            ((float4*)out)[(size_t)np * 16 + 2 * sl]     = o0;
            ((float4*)out)[(size_t)np * 16 + 2 * sl + 1] = o1;
        }
        b0 = b1; e0 = e1; idx0 = idx1; self0 = self1; dv0 = dv1;
        b1 = b2; e1 = e2;
    }
}

// ---------------- launcher ----------------

extern "C" void kernel_launch(void* const* d_in, const int* in_sizes, int n_in,
                              void* d_out, int out_size, void* d_ws, size_t ws_size,
                              hipStream_t stream) {
    const float* x  = (const float*)d_in[0];
    const int*   ei = (const int*)d_in[1];   // int32 on the wire
    const float* W1 = (const float*)d_in[2];
    const float* b1 = (const float*)d_in[3];
    const float* W2 = (const float*)d_in[4];
    const float* b2 = (const float*)d_in[5];
    float* out = (float*)d_out;

    const int N = in_sizes[0] / 128;   // 100000
    const int E = in_sizes[1] / 2;     // 1600000
    const int* srcv = ei;
    const int* dstv = ei + E;

    const int NBC    = (N + 255) >> CSHIFT;           // 391 coarse buckets
    const int NBLK_E = (E + EPB - 1) / EPB;           // 391 edge blocks
    const int HLEN   = NBC * NBLK_E;                  // 152,881
    const int NCHH   = (HLEN + CHUNK - 1) / CHUNK;    // 150

    // workspace layout (segments padded to 64 B; hs1/out1 16-B aligned for dwordx4)
    char* p = (char*)d_ws;
    int*      row_ptr    = (int*)p;      p += (((size_t)N + 64) * 4 + 63) & ~(size_t)63;
    int*      chunk_sums = (int*)p;      p += 1024;
    int*      hist       = (int*)p;      p += (((size_t)HLEN + 64) * 4 + 63) & ~(size_t)63;
    int*      csr_src    = (int*)p;      p += ((size_t)E * 4 + 63) & ~(size_t)63;
    float*    dinv       = (float*)p;    p += (((size_t)N + 64) * 4 + 63) & ~(size_t)63;
    _Float16* wf1g       = (_Float16*)p; p += 8 * 4 * 64 * 16;   // 32 KB blob
    _Float16* wf2g       = (_Float16*)p; p += 4 * 4 * 64 * 16;   // 16 KB blob
    __half*   hs1        = (__half*)p;   p += (size_t)N * 128 * 2;
    __half*   out1       = (__half*)p;   p += (size_t)N * 128 * 2;
    int*      pairs      = (int*)out1;      // alias: out1 dead until after CSR build (E*4 <= N*256)
    __half*   hs2        = hs1;             // hs1 dead once out1 complete

    // ---- CSR build + W prep (histogram[+wprep] -> scan -> partition -> finalize) ----
    hist_kernel<<<NBLK_E, 256, 0, stream>>>(dstv, hist, W1, W2, wf1g, wf2g, E, NBC, NBLK_E);
    scanA_kernel<<<NCHH, 256, 0, stream>>>(hist, hist, chunk_sums, HLEN);  // in-place safe
    scanB_kernel<<<1, 256, 0, stream>>>(chunk_sums, NCHH);
    partition_kernel<<<NBLK_E, 256, 0, stream>>>(srcv, dstv, hist, chunk_sums, pairs,
                                                 E, NBC, NBLK_E);
    bucket_finalize_kernel<<<NBC, 256, 0, stream>>>(pairs, hist, chunk_sums, row_ptr, dinv,
                                                    csr_src, N, E, NBC, NBLK_E);

    // ---- layer 1: MFMA GEMM (fp32 in, fp16 out), agg -> fp16 out1 ----
    gemm_mfma_kernel<128, false, float><<<(N + 63) / 64, 256, 0, stream>>>(x, wf1g, dinv, hs1, N);
    agg_pull128_kernel<<<AGG_BLOCKS, TPB, 0, stream>>>(hs1, csr_src, row_ptr, dinv, b1, out1, N);

    // ---- layer 2: MFMA GEMM (fp16 in w/ fused ReLU), agg -> fp32 d_out ----
    gemm_mfma_kernel<64, true, _Float16><<<(N + 63) / 64, 256, 0, stream>>>(
        (const _Float16*)out1, wf2g, dinv, hs2, N);
    agg_pull64_kernel<<<AGG_BLOCKS, TPB, 0, stream>>>(hs2, csr_src, row_ptr, dinv, b2, out, N);
}